// Round 6
// baseline (508.831 us; speedup 1.0000x reference)
//
#include <hip/hip_runtime.h>
#include <hip/hip_bf16.h>

// Joiner: out[m, v] = tanh(enc[b_m, t_m, :] + dec[b_m, u_m, :]) @ W[v, :]^T + bias[v]
// M ~ 295k rows, K = 512, V = 500 (padded to 512).
// r6: swapped-operand MFMA  acc = mfma(W_frag, act_frag)  ->  each lane's f32x4
// spans 4 consecutive output COLUMNS -> direct coalesced float4 global stores.
// No epilogue LDS round-trip, no Obuf, 2 barriers/tile. Natural block order
// (XCD swizzle reverted: it thrashed L3 -> FETCH 48->112MB in r5).

typedef __attribute__((ext_vector_type(8))) short short8;   // 8 bf16
typedef __attribute__((ext_vector_type(4))) float f32x4;    // MFMA acc

__device__ __forceinline__ unsigned short f2bf(float v) {
    unsigned int u = __float_as_uint(v);
    u += 0x7fffu + ((u >> 16) & 1u);
    return (unsigned short)(u >> 16);
}

__device__ __forceinline__ float tanh_fast(float x) {
    float e = __builtin_amdgcn_exp2f(fabsf(x) * -2.8853900817779268f);
    float r = (1.0f - e) * __builtin_amdgcn_rcpf(1.0f + e);
    return copysignf(r, x);
}

// W (500x512 f32) -> 512x512 bf16 (rows 500..511 zero) in workspace.
__global__ void prep_w_kernel(const float* __restrict__ W, unsigned short* __restrict__ Wbf) {
    const int i = blockIdx.x * blockDim.x + threadIdx.x;
    const int base = i << 2;
    const int n = base >> 9;
    const int k = base & 511;
    float4 v = make_float4(0.f, 0.f, 0.f, 0.f);
    if (n < 500) v = *reinterpret_cast<const float4*>(W + ((size_t)n << 9) + k);
    uint2 p;
    p.x = (unsigned int)f2bf(v.x) | ((unsigned int)f2bf(v.y) << 16);
    p.y = (unsigned int)f2bf(v.z) | ((unsigned int)f2bf(v.w) << 16);
    *reinterpret_cast<uint2*>(Wbf + base) = p;
}

// Block: 64 rows x 512 cols. 512 threads = 8 waves, wave tile 64 rows x 64 cols.
template<bool USE_WS>
__global__ __launch_bounds__(512, 4)
void joiner_gemm_kernel(const float* __restrict__ enc, const float* __restrict__ dec,
                        const float* __restrict__ W, const float* __restrict__ bias,
                        const int* __restrict__ b_idx, const int* __restrict__ t_idx,
                        const int* __restrict__ u_idx,
                        const unsigned short* __restrict__ Wbf,
                        float* __restrict__ out, int M)
{
    __shared__ unsigned char Abuf[64 * 512 * 2];   // 64 KB bf16, XOR-swizzled
    __shared__ unsigned int eoffs[64];
    __shared__ unsigned int doffs[64];

    const int tid = threadIdx.x;
    const int m0 = blockIdx.x * 64;     // natural order: concurrent blocks share
                                        // the same batch's enc/dec rows in L2/L3

    // ------- Phase 0: gather offsets -------
    if (tid < 64) {
        const int rc = min(m0 + tid, M - 1);
        const unsigned bi = (unsigned)b_idx[rc];
        eoffs[tid] = ((bi << 9) + (unsigned)t_idx[rc]) << 9;   // (bi*512+ti)*512
        doffs[tid] = ((bi << 6) + (unsigned)u_idx[rc]) << 9;   // (bi*64 +ui)*512
    }
    __syncthreads();

    // ------- Phase 1: activations -> LDS (bf16), 4 rows/pass, depth-3 pipeline -------
    {
        const int rr = tid >> 7;          // 0..3 : row within quad
        const int kq = tid & 127;         // float4 chunk in 512-wide row
        const int kq4 = kq << 2;

        float4 es[3], dsv[3];
        #pragma unroll
        for (int i = 0; i < 3; ++i) {
            es[i]  = *reinterpret_cast<const float4*>(enc + eoffs[i * 4 + rr] + kq4);
            dsv[i] = *reinterpret_cast<const float4*>(dec + doffs[i * 4 + rr] + kq4);
        }
        #pragma unroll
        for (int p = 0; p < 16; ++p) {
            const int s = p % 3;
            const float4 e = es[s];
            const float4 d = dsv[s];
            if (p + 3 < 16) {
                es[s]  = *reinterpret_cast<const float4*>(enc + eoffs[(p + 3) * 4 + rr] + kq4);
                dsv[s] = *reinterpret_cast<const float4*>(dec + doffs[(p + 3) * 4 + rr] + kq4);
            }
            uint2 packed;
            packed.x = (unsigned int)f2bf(tanh_fast(e.x + d.x)) |
                       ((unsigned int)f2bf(tanh_fast(e.y + d.y)) << 16);
            packed.y = (unsigned int)f2bf(tanh_fast(e.z + d.z)) |
                       ((unsigned int)f2bf(tanh_fast(e.w + d.w)) << 16);
            const int r = p * 4 + rr;
            const int byteoff = (r * 1024 + kq * 8) ^ ((r & 7) << 4);
            *reinterpret_cast<uint2*>(&Abuf[byteoff]) = packed;
        }
    }

    // ------- Phase 2: MFMA GEMM (W as A-operand, act as B-operand) -------
    const int lane = tid & 63;
    const int wv   = tid >> 6;          // wave 0..7 -> cols [wv*64, wv*64+64)
    const int l15  = lane & 15;
    const int lk   = lane >> 4;
    const int n_wave = wv << 6;
    const int a_swz  = (l15 & 7) << 4;

    f32x4 acc[4][4];
    #pragma unroll
    for (int mf = 0; mf < 4; ++mf)
        #pragma unroll
        for (int nf = 0; nf < 4; ++nf)
            acc[mf][nf] = (f32x4)(0.0f);

    const unsigned short* wp = USE_WS ? (Wbf + (((size_t)(n_wave + l15)) << 9) + (lk << 3)) : nullptr;
    const float* wpf = USE_WS ? nullptr : (W + (((size_t)(n_wave + l15)) << 9) + (lk << 3));
    const int colbase = n_wave + l15;

    auto loadB = [&](int ks, int nf) -> short8 {
        if constexpr (USE_WS) {
            return *reinterpret_cast<const short8*>(wp + nf * 8192 + ks * 32);
        } else {
            short8 b;
            float4 w0 = make_float4(0,0,0,0), w1 = make_float4(0,0,0,0);
            if (colbase + nf * 16 < 500) {
                const float4* q = reinterpret_cast<const float4*>(wpf + nf * 8192 + ks * 32);
                w0 = q[0]; w1 = q[1];
            }
            b[0] = (short)f2bf(w0.x); b[1] = (short)f2bf(w0.y);
            b[2] = (short)f2bf(w0.z); b[3] = (short)f2bf(w0.w);
            b[4] = (short)f2bf(w1.x); b[5] = (short)f2bf(w1.y);
            b[6] = (short)f2bf(w1.z); b[7] = (short)f2bf(w1.w);
            return b;
        }
    };

    short8 Bc[4], Bn[4];
    #pragma unroll
    for (int nf = 0; nf < 4; ++nf) Bc[nf] = loadB(0, nf);

    __syncthreads();

    #pragma unroll 4
    for (int ks = 0; ks < 16; ++ks) {
        if (ks < 15) {
            #pragma unroll
            for (int nf = 0; nf < 4; ++nf) Bn[nf] = loadB(ks + 1, nf);
        }
        short8 a[4];
        #pragma unroll
        for (int mf = 0; mf < 4; ++mf) {
            const int addr = (((mf * 16 + l15) << 10) + ks * 64 + lk * 16) ^ a_swz;
            a[mf] = *reinterpret_cast<const short8*>(&Abuf[addr]);
        }
        __builtin_amdgcn_s_setprio(1);
        #pragma unroll
        for (int mf = 0; mf < 4; ++mf)
            #pragma unroll
            for (int nf = 0; nf < 4; ++nf)
                // SWAPPED: W frag as A-operand, activation frag as B-operand.
                // D[row = W-col = lk*4+j][col = act-row = l15]
                acc[mf][nf] = __builtin_amdgcn_mfma_f32_16x16x32_bf16(Bc[nf], a[mf], acc[mf][nf], 0, 0, 0);
        __builtin_amdgcn_s_setprio(0);
        #pragma unroll
        for (int nf = 0; nf < 4; ++nf) Bc[nf] = Bn[nf];
    }

    // ------- Epilogue: bias + DIRECT coalesced float4 stores (no LDS) -------
    // lane (l15, lk): acc[mf][nf][j] = out[m0 + mf*16 + l15][wv*64 + nf*16 + lk*4 + j]
    float4 bv4[4];
    #pragma unroll
    for (int nf = 0; nf < 4; ++nf) {
        const int colb = n_wave + nf * 16 + (lk << 2);
        bv4[nf] = (colb < 500) ? *reinterpret_cast<const float4*>(bias + colb)
                               : make_float4(0.f, 0.f, 0.f, 0.f);
    }
    #pragma unroll
    for (int mf = 0; mf < 4; ++mf) {
        const int row = m0 + mf * 16 + l15;
        if (row < M) {
            float* op = out + (size_t)row * 500;
            #pragma unroll
            for (int nf = 0; nf < 4; ++nf) {
                const int colb = n_wave + nf * 16 + (lk << 2);
                if (colb < 500) {
                    float4 v;
                    v.x = acc[mf][nf][0] + bv4[nf].x;
                    v.y = acc[mf][nf][1] + bv4[nf].y;
                    v.z = acc[mf][nf][2] + bv4[nf].z;
                    v.w = acc[mf][nf][3] + bv4[nf].w;
                    *reinterpret_cast<float4*>(op + colb) = v;
                }
            }
        }
    }
}

extern "C" void kernel_launch(void* const* d_in, const int* in_sizes, int n_in,
                              void* d_out, int out_size, void* d_ws, size_t ws_size,
                              hipStream_t stream) {
    const float* enc  = (const float*)d_in[0];
    const float* dec  = (const float*)d_in[1];
    const float* W    = (const float*)d_in[2];
    const float* bias = (const float*)d_in[3];
    const int* bi = (const int*)d_in[4];
    const int* ti = (const int*)d_in[5];
    const int* ui = (const int*)d_in[6];
    float* out = (float*)d_out;

    const int M = in_sizes[4];
    const int grid = (M + 63) / 64;

    if (ws_size >= (size_t)(512 * 512 * 2)) {
        prep_w_kernel<<<256, 256, 0, stream>>>(W, (unsigned short*)d_ws);
        joiner_gemm_kernel<true><<<grid, 512, 0, stream>>>(
            enc, dec, W, bias, bi, ti, ui, (const unsigned short*)d_ws, out, M);
    } else {
        joiner_gemm_kernel<false><<<grid, 512, 0, stream>>>(
            enc, dec, W, bias, bi, ti, ui, nullptr, out, M);
    }
}

// Round 8
// 410.678 us; speedup vs baseline: 1.2390x; 1.2390x over previous
//
#include <hip/hip_runtime.h>
#include <hip/hip_bf16.h>

// Joiner: out[m, v] = tanh(enc[b_m, t_m, :] + dec[b_m, u_m, :]) @ W[v, :]^T + bias[v]
// M ~ 295k rows, K = 512, V = 500 (padded to 512).
// r8 = r5 structure (8 waves x 64x64 tiles, 4 waves/SIMD, Obuf coalesced epilogue,
// natural block order) + NONTEMPORAL output stores (via ext_vector f32x4 -- HIP
// float4 is a class type the builtin rejects): keep the 590MB write stream out
// of L2 so W and gather rows stay L2-resident.

typedef __attribute__((ext_vector_type(8))) short short8;   // 8 bf16
typedef __attribute__((ext_vector_type(4))) float f32x4;    // MFMA acc / NT store

__device__ __forceinline__ unsigned short f2bf(float v) {
    unsigned int u = __float_as_uint(v);
    u += 0x7fffu + ((u >> 16) & 1u);
    return (unsigned short)(u >> 16);
}

__device__ __forceinline__ float tanh_fast(float x) {
    float e = __builtin_amdgcn_exp2f(fabsf(x) * -2.8853900817779268f);
    float r = (1.0f - e) * __builtin_amdgcn_rcpf(1.0f + e);
    return copysignf(r, x);
}

// W (500x512 f32) -> 512x512 bf16 (rows 500..511 zero) in workspace.
__global__ void prep_w_kernel(const float* __restrict__ W, unsigned short* __restrict__ Wbf) {
    const int i = blockIdx.x * blockDim.x + threadIdx.x;
    const int base = i << 2;
    const int n = base >> 9;
    const int k = base & 511;
    float4 v = make_float4(0.f, 0.f, 0.f, 0.f);
    if (n < 500) v = *reinterpret_cast<const float4*>(W + ((size_t)n << 9) + k);
    uint2 p;
    p.x = (unsigned int)f2bf(v.x) | ((unsigned int)f2bf(v.y) << 16);
    p.y = (unsigned int)f2bf(v.z) | ((unsigned int)f2bf(v.w) << 16);
    *reinterpret_cast<uint2*>(Wbf + base) = p;
}

// Block: 64 rows x 512 cols. 512 threads = 8 waves, wave tile 64x64.
template<bool USE_WS>
__global__ __launch_bounds__(512, 4)
void joiner_gemm_kernel(const float* __restrict__ enc, const float* __restrict__ dec,
                        const float* __restrict__ W, const float* __restrict__ bias,
                        const int* __restrict__ b_idx, const int* __restrict__ t_idx,
                        const int* __restrict__ u_idx,
                        const unsigned short* __restrict__ Wbf,
                        float* __restrict__ out, int M)
{
    // Union: phase1/2 = [64][512] bf16 (64KB, XOR-swizzled); epilogue = [64][257] f32.
    __shared__ unsigned char Abuf[65792];
    __shared__ unsigned int eoffs[64];
    __shared__ unsigned int doffs[64];

    const int tid = threadIdx.x;
    const int m0 = blockIdx.x * 64;     // natural order: concurrent blocks share
                                        // enc/dec rows + W in the XCD's L2

    // ------- Phase 0: gather offsets -------
    if (tid < 64) {
        const int rc = min(m0 + tid, M - 1);
        const unsigned bi = (unsigned)b_idx[rc];
        eoffs[tid] = ((bi << 9) + (unsigned)t_idx[rc]) << 9;   // (bi*512+ti)*512
        doffs[tid] = ((bi << 6) + (unsigned)u_idx[rc]) << 9;   // (bi*64 +ui)*512
    }
    __syncthreads();

    // ------- Phase 1: activations -> LDS (bf16), 4 rows/pass, depth-3 pipeline -------
    {
        const int rr = tid >> 7;          // 0..3 : row within quad
        const int kq = tid & 127;         // float4 chunk in 512-wide row
        const int kq4 = kq << 2;

        float4 es[3], dsv[3];
        #pragma unroll
        for (int i = 0; i < 3; ++i) {
            es[i]  = *reinterpret_cast<const float4*>(enc + eoffs[i * 4 + rr] + kq4);
            dsv[i] = *reinterpret_cast<const float4*>(dec + doffs[i * 4 + rr] + kq4);
        }
        #pragma unroll
        for (int p = 0; p < 16; ++p) {
            const int s = p % 3;
            const float4 e = es[s];
            const float4 d = dsv[s];
            if (p + 3 < 16) {
                es[s]  = *reinterpret_cast<const float4*>(enc + eoffs[(p + 3) * 4 + rr] + kq4);
                dsv[s] = *reinterpret_cast<const float4*>(dec + doffs[(p + 3) * 4 + rr] + kq4);
            }
            uint2 packed;
            packed.x = (unsigned int)f2bf(tanh_fast(e.x + d.x)) |
                       ((unsigned int)f2bf(tanh_fast(e.y + d.y)) << 16);
            packed.y = (unsigned int)f2bf(tanh_fast(e.z + d.z)) |
                       ((unsigned int)f2bf(tanh_fast(e.w + d.w)) << 16);
            const int r = p * 4 + rr;
            const int byteoff = (r * 1024 + kq * 8) ^ ((r & 7) << 4);
            *reinterpret_cast<uint2*>(&Abuf[byteoff]) = packed;
        }
    }

    // ------- Phase 2: MFMA GEMM, wave tile 64x64, depth-1 B prefetch -------
    const int lane = tid & 63;
    const int wv   = tid >> 6;          // wave 0..7 -> cols [wv*64, wv*64+64)
    const int l15  = lane & 15;
    const int lk   = lane >> 4;
    const int n_wave = wv << 6;
    const int a_swz  = (l15 & 7) << 4;

    f32x4 acc[4][4];
    #pragma unroll
    for (int mf = 0; mf < 4; ++mf)
        #pragma unroll
        for (int nf = 0; nf < 4; ++nf)
            acc[mf][nf] = (f32x4)(0.0f);

    const unsigned short* wp = USE_WS ? (Wbf + (((size_t)(n_wave + l15)) << 9) + (lk << 3)) : nullptr;
    const float* wpf = USE_WS ? nullptr : (W + (((size_t)(n_wave + l15)) << 9) + (lk << 3));
    const int colbase = n_wave + l15;

    auto loadB = [&](int ks, int nf) -> short8 {
        if constexpr (USE_WS) {
            return *reinterpret_cast<const short8*>(wp + nf * 8192 + ks * 32);
        } else {
            short8 b;
            float4 w0 = make_float4(0,0,0,0), w1 = make_float4(0,0,0,0);
            if (colbase + nf * 16 < 500) {
                const float4* q = reinterpret_cast<const float4*>(wpf + nf * 8192 + ks * 32);
                w0 = q[0]; w1 = q[1];
            }
            b[0] = (short)f2bf(w0.x); b[1] = (short)f2bf(w0.y);
            b[2] = (short)f2bf(w0.z); b[3] = (short)f2bf(w0.w);
            b[4] = (short)f2bf(w1.x); b[5] = (short)f2bf(w1.y);
            b[6] = (short)f2bf(w1.z); b[7] = (short)f2bf(w1.w);
            return b;
        }
    };

    short8 Bc[4], Bn[4];
    #pragma unroll
    for (int nf = 0; nf < 4; ++nf) Bc[nf] = loadB(0, nf);

    __syncthreads();

    #pragma unroll 4
    for (int ks = 0; ks < 16; ++ks) {
        if (ks < 15) {
            #pragma unroll
            for (int nf = 0; nf < 4; ++nf) Bn[nf] = loadB(ks + 1, nf);
        }
        short8 a[4];
        #pragma unroll
        for (int mf = 0; mf < 4; ++mf) {
            const int addr = (((mf * 16 + l15) << 10) + ks * 64 + lk * 16) ^ a_swz;
            a[mf] = *reinterpret_cast<const short8*>(&Abuf[addr]);
        }
        __builtin_amdgcn_s_setprio(1);
        #pragma unroll
        for (int mf = 0; mf < 4; ++mf)
            #pragma unroll
            for (int nf = 0; nf < 4; ++nf)
                acc[mf][nf] = __builtin_amdgcn_mfma_f32_16x16x32_bf16(a[mf], Bc[nf], acc[mf][nf], 0, 0, 0);
        __builtin_amdgcn_s_setprio(0);
        #pragma unroll
        for (int nf = 0; nf < 4; ++nf) Bc[nf] = Bn[nf];
    }

    // ------- Epilogue: bias + coalesced NONTEMPORAL stores via Obuf -------
    #pragma unroll
    for (int nf = 0; nf < 4; ++nf) {
        const int col = n_wave + nf * 16 + l15;
        const float bv = (col < 500) ? bias[col] : 0.0f;
        #pragma unroll
        for (int mf = 0; mf < 4; ++mf)
            #pragma unroll
            for (int j = 0; j < 4; ++j)
                acc[mf][nf][j] += bv;
    }

    float* Obuf = reinterpret_cast<float*>(Abuf);   // [64][257] f32
    #pragma unroll
    for (int h = 0; h < 2; ++h) {
        __syncthreads();                  // protects Abuf/Obuf reuse
        if ((wv >> 2) == h) {
            const int lcol = (wv & 3) << 6;
            #pragma unroll
            for (int mf = 0; mf < 4; ++mf)
                #pragma unroll
                for (int nf = 0; nf < 4; ++nf)
                    #pragma unroll
                    for (int j = 0; j < 4; ++j) {
                        const int r = mf * 16 + lk * 4 + j;
                        Obuf[r * 257 + lcol + nf * 16 + l15] = acc[mf][nf][j];
                    }
        }
        __syncthreads();
        // 64 rows x 64 float4-chunks per half; 1KB contiguous per wave per iter.
        // Nontemporal: don't allocate the write stream in L2/L3.
        #pragma unroll
        for (int i = 0; i < 8; ++i) {
            const int linear = i * 512 + tid;
            const int r  = linear >> 6;
            const int c4 = linear & 63;
            const int row = m0 + r;
            const int col = (h << 8) + (c4 << 2);
            if (row < M && col < 500) {
                const f32x4 v = *reinterpret_cast<const f32x4*>(&Obuf[r * 257 + (c4 << 2)]);
                __builtin_nontemporal_store(v, reinterpret_cast<f32x4*>(&out[(size_t)row * 500 + col]));
            }
        }
    }
}

extern "C" void kernel_launch(void* const* d_in, const int* in_sizes, int n_in,
                              void* d_out, int out_size, void* d_ws, size_t ws_size,
                              hipStream_t stream) {
    const float* enc  = (const float*)d_in[0];
    const float* dec  = (const float*)d_in[1];
    const float* W    = (const float*)d_in[2];
    const float* bias = (const float*)d_in[3];
    const int* bi = (const int*)d_in[4];
    const int* ti = (const int*)d_in[5];
    const int* ui = (const int*)d_in[6];
    float* out = (float*)d_out;

    const int M = in_sizes[4];
    const int grid = (M + 63) / 64;

    if (ws_size >= (size_t)(512 * 512 * 2)) {
        prep_w_kernel<<<256, 256, 0, stream>>>(W, (unsigned short*)d_ws);
        joiner_gemm_kernel<true><<<grid, 512, 0, stream>>>(
            enc, dec, W, bias, bi, ti, ui, (const unsigned short*)d_ws, out, M);
    } else {
        joiner_gemm_kernel<false><<<grid, 512, 0, stream>>>(
            enc, dec, W, bias, bi, ti, ui, nullptr, out, M);
    }
}